// Round 11
// baseline (357.184 us; speedup 1.0000x reference)
//
#include <hip/hip_runtime.h>
#include <hip/hip_bf16.h>
#include <hip/hip_fp8.h>

#define D_DIM 768
#define B_DIM 8192
#define NT 64           // tile grid dim (8192/128)
#define NTILES 2080     // NT*(NT+1)/2 upper-triangle tiles
#define BM 128
#define NCAST 512       // cast slices (16 rows each)

typedef __attribute__((ext_vector_type(4))) float f32x4;
typedef __attribute__((ext_vector_type(4))) int i32x4;
typedef __attribute__((ext_vector_type(8))) int i32x8;

// ws layout (bytes)
#define WS_XB   0                               // fp8[8192*768]    = 6,291,456
#define WS_SQ   6291456                         // float[8192]      = 32,768
#define WS_CAND 6324224                         // float[8192*64*6] = 12,582,912
#define WS_CTR  18907136                        // uint[256] control block (memset 0)
// ctr[0]=castTkt  ctr[1]=finCnt  ctr[2]=acc(float)  ctr[8+p]=castDone[p]
// ctr[72+p]=panelDone[p]

#define AGENT __HIP_MEMORY_SCOPE_AGENT

__device__ __forceinline__ void gl_lds16(const void* g, void* lds) {
  __builtin_amdgcn_global_load_lds(
      (const __attribute__((address_space(1))) unsigned int*)g,
      (__attribute__((address_space(3))) unsigned int*)lds, 16, 0, 0);
}

// branchless: maintain v[0..5] = six smallest seen, sorted ascending.
__device__ __forceinline__ void ins6(float c, float* v) {
  v[5] = fminf(v[5], c);
#pragma unroll
  for (int s = 5; s > 0; --s) {
    float lo = fminf(v[s - 1], v[s]);
    float hi = fmaxf(v[s - 1], v[s]);
    v[s - 1] = lo;
    v[s] = hi;
  }
}

// band-blocked triangle order (16x16-tile blocks, rt-major inside). g in [0,2080).
__device__ __forceinline__ void tile_decode(int g, int& rt, int& ct) {
  int base = 0;
  for (int s = 0; s < 4; ++s) {
    for (int cb = s; cb < 4; ++cb) {
      const int sz = (cb == s) ? 136 : 256;
      if (g < base + sz) {
        int loc = g - base;
        if (cb == s) {
          int r = 0;
          while (loc >= 16 - r) {
            loc -= 16 - r;
            ++r;
          }
          rt = s * 16 + r;
          ct = cb * 16 + r + loc;
        } else {
          rt = s * 16 + (loc >> 4);
          ct = cb * 16 + (loc & 15);
        }
        return;
      }
      base += sz;
    }
  }
  rt = 0;
  ct = 0;
}

// ---- single fused kernel: cast (ticket) -> Gram+top6 -> merge (last-toucher) ----
// Gemm core identical to the round-10 verified kernel (MX-fp8 K=128, dbuf,
// slot swizzle, band-blocked XCD tiles). Cross-XCD visibility: xb/sq/cand are
// written with agent-scope atomic stores (bypass non-coherent per-XCD L2, land
// at the L3 coherence point); consumers' plain reads are first-touch-after-flag.
#define ABUF(b) ((b) * 32768)
#define BBUF(b) ((b) * 32768 + 16384)
#define VMW(N) asm volatile("s_waitcnt vmcnt(" #N ")" ::: "memory")
#define BAR()                         \
  {                                   \
    asm volatile("" ::: "memory");    \
    __builtin_amdgcn_s_barrier();     \
    asm volatile("" ::: "memory");    \
  }

__global__ __launch_bounds__(256, 2) void knn_fused(
    const float* __restrict__ x, unsigned char* __restrict__ xb,
    float* __restrict__ sq, float* __restrict__ cand,
    unsigned int* __restrict__ ctr, float* __restrict__ out) {
  __shared__ __align__(16) char smem[65536];
  __shared__ int sTick;
  __shared__ int finP[2];
  __shared__ float red[4];

  const int t = threadIdx.x;
  const int lane = t & 63, w = t >> 6;
  const int wm = w >> 1, wn = w & 1;  // 2x2 wave grid; wave tile 64x64
  const int quad = lane >> 4, m16 = lane & 15;
  float* accF = (float*)&ctr[2];

  // ---------------- phase 1: cast duty via global ticket ----------------
  if (t == 0) sTick = (int)atomicAdd(&ctr[0], 1u);
  __syncthreads();
  const int tick = sTick;
  if (tick < NCAST) {
    // slice = rows tick*16 .. +15; wave w handles rows w*4..w*4+3
#pragma unroll
    for (int rr = 0; rr < 4; ++rr) {
      const int row = tick * 16 + w * 4 + rr;
      const f32x4* xr = (const f32x4*)(x + (size_t)row * D_DIM);
      unsigned int* xbr = (unsigned int*)(xb + (size_t)row * D_DIM);
      float s = 0.0f;
#pragma unroll
      for (int c = 0; c < 3; ++c) {
        const int idx = c * 64 + lane;
        f32x4 v = xr[idx];
        unsigned int p = 0;
#pragma unroll
        for (int e = 0; e < 4; ++e) {
          __hip_fp8_e4m3 h(v[e]);
          const float d = (float)h;
          s += d * d;
          p |= ((unsigned int)h.__x) << (8 * e);
        }
        __hip_atomic_store(&xbr[idx], p, __ATOMIC_RELAXED, AGENT);
      }
#pragma unroll
      for (int off = 32; off > 0; off >>= 1) s += __shfl_down(s, off, 64);
      if (lane == 0) __hip_atomic_store(&sq[row], s, __ATOMIC_RELAXED, AGENT);
    }
    __syncthreads();
    if (t == 0) {
      __threadfence();
      atomicAdd(&ctr[8 + (tick >> 3)], 1u);  // panel = 8 slices
    }
  }

  // ---------------- phase 2: one Gram tile (round-10 core) ----------------
  const int g = (blockIdx.x & 7) * (NTILES / 8) + (blockIdx.x >> 3);
  int rt, ct;
  tile_decode(g, rt, ct);
  const bool offdiag = (ct > rt);
  const int rowBase = rt * BM, colBase = ct * BM;

  // wait for both panels cast (acquire; producers are the first 512 blocks to
  // run, they cast unconditionally -> deadlock-free)
  if (t == 0) {
    while (__hip_atomic_load(&ctr[8 + rt], __ATOMIC_ACQUIRE, AGENT) < 8u ||
           __hip_atomic_load(&ctr[8 + ct], __ATOMIC_ACQUIRE, AGENT) < 8u)
      __builtin_amdgcn_s_sleep(8);
  }
  __syncthreads();

  // staging: thread t covers rows (t>>3)+32q, slot t&7; inverse slot swizzle on
  // the global source. (row&3) and ((row>>2)&1) are invariant under row+=32.
  const int sR = t >> 3, sS = t & 7;
  const int q_src = ((sS >> 1) - sR) & 3;
  const int h_src = ((sS & 1) - (sR >> 2)) & 1;
  const int srcOff = q_src * 32 + h_src * 16;
  const unsigned char* pA = xb + (size_t)(rowBase + sR) * D_DIM + srcOff;
  const unsigned char* pB = xb + (size_t)(colBase + sR) * D_DIM + srcOff;

  const int pairOff = ((quad + m16) & 3) * 32;
  const int bitOff = ((m16 >> 2) & 1) * 16;
  const int laneLo = m16 * 128 + pairOff + bitOff;
  const int laneHi = m16 * 128 + pairOff + (bitOff ^ 16);
  const int aRow = wm * 8192;
  const int bRow = wn * 8192;

  float rsq[16];
#pragma unroll
  for (int i = 0; i < 4; ++i)
#pragma unroll
    for (int r = 0; r < 4; ++r)
      rsq[i * 4 + r] = sq[rowBase + wm * 64 + i * 16 + quad * 4 + r];
  float csq[4];
#pragma unroll
  for (int j = 0; j < 4; ++j) csq[j] = sq[colBase + wn * 64 + j * 16 + m16];

  f32x4 acv[4][4];
  const f32x4 zero = {0.0f, 0.0f, 0.0f, 0.0f};
#pragma unroll
  for (int i = 0; i < 4; ++i)
#pragma unroll
    for (int j = 0; j < 4; ++j) acv[i][j] = zero;

#define STAGE(P, KOFF, REGION)                                          \
  {                                                                     \
    _Pragma("unroll") for (int q = 0; q < 4; ++q)                       \
        gl_lds16((P) + (KOFF) + q * 32 * D_DIM,                         \
                 smem + (REGION) + q * 4096 + t * 16);                  \
  }

  i32x8 aF[4], bF[4];
#define LDA(BASE)                                                            \
  {                                                                          \
    _Pragma("unroll") for (int ii = 0; ii < 4; ++ii) {                       \
      i32x4 lo = *(const i32x4*)(smem + (BASE) + aRow + ii * 2048 + laneLo); \
      i32x4 hi = *(const i32x4*)(smem + (BASE) + aRow + ii * 2048 + laneHi); \
      __builtin_memcpy(&aF[ii], &lo, 16);                                    \
      __builtin_memcpy(((char*)&aF[ii]) + 16, &hi, 16);                      \
    }                                                                        \
  }
#define LDB(BASE)                                                            \
  {                                                                          \
    _Pragma("unroll") for (int j = 0; j < 4; ++j) {                          \
      i32x4 lo = *(const i32x4*)(smem + (BASE) + bRow + j * 2048 + laneLo);  \
      i32x4 hi = *(const i32x4*)(smem + (BASE) + bRow + j * 2048 + laneHi);  \
      __builtin_memcpy(&bF[j], &lo, 16);                                     \
      __builtin_memcpy(((char*)&bF[j]) + 16, &hi, 16);                       \
    }                                                                        \
  }
#define MFMAS16                                                              \
  {                                                                          \
    __builtin_amdgcn_s_setprio(1);                                           \
    _Pragma("unroll") for (int ii = 0; ii < 4; ++ii)                         \
        _Pragma("unroll") for (int j = 0; j < 4; ++j)                        \
            acv[ii][j] = __builtin_amdgcn_mfma_scale_f32_16x16x128_f8f6f4(   \
                aF[ii], bF[j], acv[ii][j], 0, 0, 0, 0x7F7F7F7F, 0,           \
                0x7F7F7F7F);                                                 \
    __builtin_amdgcn_s_setprio(0);                                           \
  }

  STAGE(pA, 0, ABUF(0));
  STAGE(pB, 0, BBUF(0));

#pragma unroll
  for (int s = 0; s < 6; ++s) {
    const int b = s & 1;
    if (s < 5) {
      STAGE(pA, (s + 1) * 128, ABUF(b ^ 1));
      STAGE(pB, (s + 1) * 128, BBUF(b ^ 1));
    }
    if (s < 5) {
      VMW(8);
    } else {
      VMW(0);
    }
    BAR();
    LDA(ABUF(b));
    LDB(BBUF(b));
    MFMAS16;
    BAR();
  }

  // ---------------- epilogue: top-6, split row/col duty ----------------
  float* distS = (float*)smem;             // [64][132] f32 = 33792 B
  float* rsqS = (float*)(smem + 33792);    // [64] f32
  float colrun[6];
#pragma unroll
  for (int q = 0; q < 6; ++q) colrun[q] = 1e30f;

#pragma unroll
  for (int gg = 0; gg < 2; ++gg) {
    BAR();
    if (wm == gg) {
#pragma unroll
      for (int ii = 0; ii < 4; ++ii)
#pragma unroll
        for (int j = 0; j < 4; ++j)
#pragma unroll
          for (int r = 0; r < 4; ++r)
            distS[(ii * 16 + quad * 4 + r) * 132 + wn * 64 + j * 16 + m16] =
                csq[j] - 2.0f * acv[ii][j][r];
      if (wn == 0 && m16 == 0) {
#pragma unroll
        for (int ii = 0; ii < 4; ++ii)
#pragma unroll
          for (int r = 0; r < 4; ++r)
            rsqS[ii * 16 + quad * 4 + r] = rsq[ii * 4 + r];
      }
    }
    BAR();
    if (t < 128) {
      const int row_l = t >> 1, half = t & 1;
      const float* drow = distS + row_l * 132 + half * 64;
      float v[6];
#pragma unroll
      for (int q = 0; q < 6; ++q) v[q] = 1e30f;
#pragma unroll
      for (int k = 0; k < 16; ++k) {
        f32x4 dv = *(const f32x4*)(drow + k * 4);
        ins6(dv[0], v);
        ins6(dv[1], v);
        ins6(dv[2], v);
        ins6(dv[3], v);
      }
      float o[6];
#pragma unroll
      for (int q = 0; q < 6; ++q) o[q] = __shfl_xor(v[q], 1, 64);
#pragma unroll
      for (int q = 0; q < 6; ++q) ins6(o[q], v);
      if (half == 0) {
        const int grow = rowBase + gg * 64 + row_l;
        const float rq = rsqS[row_l];
        float* o6 = cand + (size_t)(grow * NT + ct) * 6;
#pragma unroll
        for (int q = 0; q < 6; ++q)
          __hip_atomic_store(&o6[q], fmaxf(v[q] + rq, 0.0f), __ATOMIC_RELAXED,
                             AGENT);
      }
    } else if (offdiag) {
      const int col = t - 128;
#pragma unroll
      for (int r = 0; r < 64; ++r) ins6(distS[r * 132 + col] + rsqS[r], colrun);
    }
  }
  if (offdiag && t >= 128) {
    const int colg = colBase + (t - 128);
    float* o6 = cand + (size_t)(colg * NT + rt) * 6;
#pragma unroll
    for (int q = 0; q < 6; ++q)
      __hip_atomic_store(&o6[q], fmaxf(colrun[q], 0.0f), __ATOMIC_RELAXED,
                         AGENT);
  }

  // ---------------- phase 3: last-toucher merges its panel ----------------
  __syncthreads();
  if (t == 0) {
    __threadfence();
    finP[0] = (atomicAdd(&ctr[72 + rt], 1u) == 63u) ? rt : -1;
    finP[1] = (offdiag && atomicAdd(&ctr[72 + ct], 1u) == 63u) ? ct : -1;
  }
  __syncthreads();
  int nfin = 0;
#pragma unroll
  for (int fi = 0; fi < 2; ++fi) {
    const int p = finP[fi];
    if (p < 0) continue;
    ++nfin;
    // merge panel p: 2 thr/row, 32 chunk-entries each
    const int row = p * 128 + (t >> 1);
    const int hf = t & 1;
    const float* cr = cand + (size_t)row * (NT * 6) + (size_t)hf * 32 * 6;
    float v[6];
#pragma unroll
    for (int q = 0; q < 6; ++q) v[q] = 1e30f;
    for (int c = 0; c < 32; ++c) {
#pragma unroll
      for (int q = 0; q < 6; ++q) {
        const float d =
            __hip_atomic_load(&cr[c * 6 + q], __ATOMIC_RELAXED, AGENT);
        ins6(d, v);
      }
    }
    float o[6];
#pragma unroll
    for (int q = 0; q < 6; ++q) o[q] = __shfl_xor(v[q], 1, 64);
#pragma unroll
    for (int q = 0; q < 6; ++q) ins6(o[q], v);
    float term = 0.0f;
    if (hf == 0) {
      // v sorted ascending on d^2: v[0] = self (~0); mean of sqrt(v[1..5])
      const float mean = (sqrtf(v[1]) + sqrtf(v[2]) + sqrtf(v[3]) +
                          sqrtf(v[4]) + sqrtf(v[5])) * 0.2f;
      term = logf(mean + 1e-8f);
    }
#pragma unroll
    for (int off = 32; off > 0; off >>= 1) term += __shfl_down(term, off, 64);
    __syncthreads();
    if (lane == 0) red[w] = term;
    __syncthreads();
    if (t == 0) atomicAdd(accF, red[0] + red[1] + red[2] + red[3]);
  }
  if (t == 0 && nfin > 0) {
    __threadfence();
    const unsigned int c = atomicAdd(&ctr[1], (unsigned int)nfin) +
                           (unsigned int)nfin;
    if (c == 64u) out[0] = -atomicAdd(accF, 0.0f) * (1.0f / 8192.0f);
  }
}

extern "C" void kernel_launch(void* const* d_in, const int* in_sizes, int n_in,
                              void* d_out, int out_size, void* d_ws, size_t ws_size,
                              hipStream_t stream) {
  const float* x = (const float*)d_in[0];
  float* out = (float*)d_out;
  char* ws = (char*)d_ws;
  unsigned char* xb = (unsigned char*)(ws + WS_XB);
  float* sq = (float*)(ws + WS_SQ);
  float* cand = (float*)(ws + WS_CAND);
  unsigned int* ctr = (unsigned int*)(ws + WS_CTR);

  hipMemsetAsync(ctr, 0, 1024, stream);
  knn_fused<<<NTILES, 256, 0, stream>>>(x, xb, sq, cand, ctr, out);
}

// Round 12
// 215.474 us; speedup vs baseline: 1.6577x; 1.6577x over previous
//
#include <hip/hip_runtime.h>
#include <hip/hip_bf16.h>
#include <hip/hip_fp8.h>

#define D_DIM 768
#define B_DIM 8192
#define NT 64           // tile grid dim (8192/128)
#define NTILES 2080     // NT*(NT+1)/2 upper-triangle tiles
#define BM 128

typedef __attribute__((ext_vector_type(4))) float f32x4;
typedef __attribute__((ext_vector_type(2))) float f32x2;
typedef __attribute__((ext_vector_type(4))) int i32x4;
typedef __attribute__((ext_vector_type(8))) int i32x8;

// ws layout (bytes)
#define WS_XB   0                               // fp8[8192*768]    = 6,291,456
#define WS_SQ   6291456                         // float[8192]      = 32,768
#define WS_CAND 6324224                         // float[8192*64*6] = 12,582,912
#define WS_CTR  18907136                        // uint[128] control block
// ctr[0]=finCnt  ctr[2]=acc(float)  ctr[8+p]=panelDone[p] (p<64)

__device__ __forceinline__ void gl_lds16(const void* g, void* lds) {
  __builtin_amdgcn_global_load_lds(
      (const __attribute__((address_space(1))) unsigned int*)g,
      (__attribute__((address_space(3))) unsigned int*)lds, 16, 0, 0);
}

// branchless: maintain v[0..5] = six smallest seen, sorted ascending.
__device__ __forceinline__ void ins6(float c, float* v) {
  v[5] = fminf(v[5], c);
#pragma unroll
  for (int s = 5; s > 0; --s) {
    float lo = fminf(v[s - 1], v[s]);
    float hi = fmaxf(v[s - 1], v[s]);
    v[s - 1] = lo;
    v[s] = hi;
  }
}

// band-blocked triangle order (16x16-tile blocks, rt-major inside). g in [0,2080).
__device__ __forceinline__ void tile_decode(int g, int& rt, int& ct) {
  int base = 0;
  for (int s = 0; s < 4; ++s) {
    for (int cb = s; cb < 4; ++cb) {
      const int sz = (cb == s) ? 136 : 256;
      if (g < base + sz) {
        int loc = g - base;
        if (cb == s) {
          int r = 0;
          while (loc >= 16 - r) {
            loc -= 16 - r;
            ++r;
          }
          rt = s * 16 + r;
          ct = cb * 16 + r + loc;
        } else {
          rt = s * 16 + (loc >> 4);
          ct = cb * 16 + (loc & 15);
        }
        return;
      }
      base += sz;
    }
  }
  rt = 0;
  ct = 0;
}

// kernel 1: cast fp32 -> fp8 e4m3 (OCP), row sum-of-squares of the DECODED fp8
// values; block 0 zeroes the control block (visible to kernel 2 at the launch
// boundary).
__global__ __launch_bounds__(256) void cast_sq_kernel(
    const float* __restrict__ x, unsigned char* __restrict__ xb,
    float* __restrict__ sq, unsigned int* __restrict__ ctr) {
  const int t = threadIdx.x;
  const int w = t >> 6, lane = t & 63;
  const int row = blockIdx.x * 4 + w;
  if (blockIdx.x == 0 && t < 128) ctr[t] = 0u;
  const f32x4* xr = (const f32x4*)(x + (size_t)row * D_DIM);
  unsigned int* xbr = (unsigned int*)(xb + (size_t)row * D_DIM);
  float s = 0.0f;
#pragma unroll
  for (int c = 0; c < 3; ++c) {
    const int idx = c * 64 + lane;
    f32x4 v = xr[idx];
    unsigned int p = 0;
#pragma unroll
    for (int e = 0; e < 4; ++e) {
      __hip_fp8_e4m3 h(v[e]);
      const float d = (float)h;
      s += d * d;
      p |= ((unsigned int)h.__x) << (8 * e);
    }
    xbr[idx] = p;
  }
#pragma unroll
  for (int off = 32; off > 0; off >>= 1) s += __shfl_down(s, off, 64);
  if (lane == 0) sq[row] = s;
}

// ------- kernel 2: MX-fp8 K=128 Gram (round-10 verified core) + fused merge -------
// After the top-6 epilogue each tile release-fences once (L2 writeback, no inv)
// and increments panelDone for its row panel (and col panel if offdiag). Each
// panel gets exactly 64 increments (64-p row-side + p col-side); the 64th
// toucher acquire-fences once (L2 inv; only 64 blocks total) and merges that
// 128-row panel: 64 chunk candidate lists -> top-6 -> sqrt/log -> atomic acc.
// Finalize via the proven acc/ticket chain. No spins anywhere.
#define ABUF(b) ((b) * 32768)
#define BBUF(b) ((b) * 32768 + 16384)
#define VMW(N) asm volatile("s_waitcnt vmcnt(" #N ")" ::: "memory")
#define BAR()                         \
  {                                   \
    asm volatile("" ::: "memory");    \
    __builtin_amdgcn_s_barrier();     \
    asm volatile("" ::: "memory");    \
  }

__global__ __launch_bounds__(256, 2) void knn_gemm_kernel(
    const unsigned char* __restrict__ xb, const float* __restrict__ sq,
    float* __restrict__ cand, unsigned int* __restrict__ ctr,
    float* __restrict__ out) {
  __shared__ __align__(16) char smem[65536];
  __shared__ int finP[2];
  __shared__ float red[4];
  const int t = threadIdx.x;
  const int lane = t & 63, w = t >> 6;
  const int wm = w >> 1, wn = w & 1;  // 2x2 wave grid; wave tile 64x64
  const int quad = lane >> 4, m16 = lane & 15;
  float* accF = (float*)&ctr[2];

  // XCD chunking (2080 = 8*260, bijective) + band-blocked decode
  const int g = (blockIdx.x & 7) * (NTILES / 8) + (blockIdx.x >> 3);
  int rt, ct;
  tile_decode(g, rt, ct);
  const bool offdiag = (ct > rt);
  const int rowBase = rt * BM, colBase = ct * BM;

  // staging: thread t covers rows (t>>3)+32q, slot t&7; inverse slot swizzle on
  // the global source. (row&3) and ((row>>2)&1) are invariant under row+=32.
  const int sR = t >> 3, sS = t & 7;
  const int q_src = ((sS >> 1) - sR) & 3;
  const int h_src = ((sS & 1) - (sR >> 2)) & 1;
  const int srcOff = q_src * 32 + h_src * 16;
  const unsigned char* pA = xb + (size_t)(rowBase + sR) * D_DIM + srcOff;
  const unsigned char* pB = xb + (size_t)(colBase + sR) * D_DIM + srcOff;

  // fragment read offsets (within a row's 128 B)
  const int pairOff = ((quad + m16) & 3) * 32;
  const int bitOff = ((m16 >> 2) & 1) * 16;
  const int laneLo = m16 * 128 + pairOff + bitOff;
  const int laneHi = m16 * 128 + pairOff + (bitOff ^ 16);
  const int aRow = wm * 8192;
  const int bRow = wn * 8192;

  float rsq[16];
#pragma unroll
  for (int i = 0; i < 4; ++i)
#pragma unroll
    for (int r = 0; r < 4; ++r)
      rsq[i * 4 + r] = sq[rowBase + wm * 64 + i * 16 + quad * 4 + r];
  float csq[4];
#pragma unroll
  for (int j = 0; j < 4; ++j) csq[j] = sq[colBase + wn * 64 + j * 16 + m16];

  f32x4 acv[4][4];
  const f32x4 zero = {0.0f, 0.0f, 0.0f, 0.0f};
#pragma unroll
  for (int i = 0; i < 4; ++i)
#pragma unroll
    for (int j = 0; j < 4; ++j) acv[i][j] = zero;

#define STAGE(P, KOFF, REGION)                                          \
  {                                                                     \
    _Pragma("unroll") for (int q = 0; q < 4; ++q)                       \
        gl_lds16((P) + (KOFF) + q * 32 * D_DIM,                         \
                 smem + (REGION) + q * 4096 + t * 16);                  \
  }

  i32x8 aF[4], bF[4];
#define LDA(BASE)                                                            \
  {                                                                          \
    _Pragma("unroll") for (int ii = 0; ii < 4; ++ii) {                       \
      i32x4 lo = *(const i32x4*)(smem + (BASE) + aRow + ii * 2048 + laneLo); \
      i32x4 hi = *(const i32x4*)(smem + (BASE) + aRow + ii * 2048 + laneHi); \
      __builtin_memcpy(&aF[ii], &lo, 16);                                    \
      __builtin_memcpy(((char*)&aF[ii]) + 16, &hi, 16);                      \
    }                                                                        \
  }
#define LDB(BASE)                                                            \
  {                                                                          \
    _Pragma("unroll") for (int j = 0; j < 4; ++j) {                          \
      i32x4 lo = *(const i32x4*)(smem + (BASE) + bRow + j * 2048 + laneLo);  \
      i32x4 hi = *(const i32x4*)(smem + (BASE) + bRow + j * 2048 + laneHi);  \
      __builtin_memcpy(&bF[j], &lo, 16);                                     \
      __builtin_memcpy(((char*)&bF[j]) + 16, &hi, 16);                       \
    }                                                                        \
  }
#define MFMAS16                                                              \
  {                                                                          \
    __builtin_amdgcn_s_setprio(1);                                           \
    _Pragma("unroll") for (int ii = 0; ii < 4; ++ii)                         \
        _Pragma("unroll") for (int j = 0; j < 4; ++j)                        \
            acv[ii][j] = __builtin_amdgcn_mfma_scale_f32_16x16x128_f8f6f4(   \
                aF[ii], bF[j], acv[ii][j], 0, 0, 0, 0x7F7F7F7F, 0,           \
                0x7F7F7F7F);                                                 \
    __builtin_amdgcn_s_setprio(0);                                           \
  }

  STAGE(pA, 0, ABUF(0));
  STAGE(pB, 0, BBUF(0));

#pragma unroll
  for (int s = 0; s < 6; ++s) {
    const int b = s & 1;
    if (s < 5) {
      STAGE(pA, (s + 1) * 128, ABUF(b ^ 1));
      STAGE(pB, (s + 1) * 128, BBUF(b ^ 1));
    }
    if (s < 5) {
      VMW(8);
    } else {
      VMW(0);
    }
    BAR();
    LDA(ABUF(b));
    LDB(BBUF(b));
    MFMAS16;
    BAR();
  }

  // ---------------- epilogue: top-6, split row/col duty (round 10) ----------------
  float* distS = (float*)smem;             // [64][132] f32 = 33792 B
  float* rsqS = (float*)(smem + 33792);    // [64] f32
  float colrun[6];
#pragma unroll
  for (int q = 0; q < 6; ++q) colrun[q] = 1e30f;

#pragma unroll
  for (int gg = 0; gg < 2; ++gg) {
    BAR();
    if (wm == gg) {
#pragma unroll
      for (int ii = 0; ii < 4; ++ii)
#pragma unroll
        for (int j = 0; j < 4; ++j)
#pragma unroll
          for (int r = 0; r < 4; ++r)
            distS[(ii * 16 + quad * 4 + r) * 132 + wn * 64 + j * 16 + m16] =
                csq[j] - 2.0f * acv[ii][j][r];
      if (wn == 0 && m16 == 0) {
#pragma unroll
        for (int ii = 0; ii < 4; ++ii)
#pragma unroll
          for (int r = 0; r < 4; ++r)
            rsqS[ii * 16 + quad * 4 + r] = rsq[ii * 4 + r];
      }
    }
    BAR();
    if (t < 128) {
      const int row_l = t >> 1, half = t & 1;
      const float* drow = distS + row_l * 132 + half * 64;
      float v[6];
#pragma unroll
      for (int q = 0; q < 6; ++q) v[q] = 1e30f;
#pragma unroll
      for (int k = 0; k < 16; ++k) {
        f32x4 dv = *(const f32x4*)(drow + k * 4);
        ins6(dv[0], v);
        ins6(dv[1], v);
        ins6(dv[2], v);
        ins6(dv[3], v);
      }
      float o[6];
#pragma unroll
      for (int q = 0; q < 6; ++q) o[q] = __shfl_xor(v[q], 1, 64);
#pragma unroll
      for (int q = 0; q < 6; ++q) ins6(o[q], v);
      if (half == 0) {
        const int grow = rowBase + gg * 64 + row_l;
        const float rq = rsqS[row_l];
        float* o6 = cand + (size_t)(grow * NT + ct) * 6;
        f32x2 w0 = {fmaxf(v[0] + rq, 0.0f), fmaxf(v[1] + rq, 0.0f)};
        f32x2 w1 = {fmaxf(v[2] + rq, 0.0f), fmaxf(v[3] + rq, 0.0f)};
        f32x2 w2 = {fmaxf(v[4] + rq, 0.0f), fmaxf(v[5] + rq, 0.0f)};
        *(f32x2*)o6 = w0;
        *(f32x2*)(o6 + 2) = w1;
        *(f32x2*)(o6 + 4) = w2;
      }
    } else if (offdiag) {
      const int col = t - 128;
#pragma unroll
      for (int r = 0; r < 64; ++r) ins6(distS[r * 132 + col] + rsqS[r], colrun);
    }
  }
  if (offdiag && t >= 128) {
    const int colg = colBase + (t - 128);
    float* o6 = cand + (size_t)(colg * NT + rt) * 6;
    f32x2 w0 = {fmaxf(colrun[0], 0.0f), fmaxf(colrun[1], 0.0f)};
    f32x2 w1 = {fmaxf(colrun[2], 0.0f), fmaxf(colrun[3], 0.0f)};
    f32x2 w2 = {fmaxf(colrun[4], 0.0f), fmaxf(colrun[5], 0.0f)};
    *(f32x2*)o6 = w0;
    *(f32x2*)(o6 + 2) = w1;
    *(f32x2*)(o6 + 4) = w2;
  }

  // ---------------- fused merge: last toucher per 128-row panel ----------------
  __syncthreads();  // all cand writes of this block drained (vmcnt 0 at barrier)
  if (t == 0) {
    __builtin_amdgcn_fence(__ATOMIC_RELEASE, "agent");  // L2 writeback, no inv
    finP[0] = (atomicAdd(&ctr[8 + rt], 1u) == 63u) ? rt : -1;
    finP[1] = (offdiag && atomicAdd(&ctr[8 + ct], 1u) == 63u) ? ct : -1;
  }
  __syncthreads();
  int nfin = 0;
  if (finP[0] >= 0 || finP[1] >= 0)
    __builtin_amdgcn_fence(__ATOMIC_ACQUIRE, "agent");  // one L2 inv, 64 blocks
#pragma unroll
  for (int fi = 0; fi < 2; ++fi) {
    const int p = finP[fi];
    if (p < 0) continue;
    ++nfin;
    // merge panel p: 2 thr/row, 32 chunk-entries (192 floats) each, plain loads
    const int prow = p * 128 + (t >> 1);
    const int hf = t & 1;
    const float* cr = cand + (size_t)prow * (NT * 6) + (size_t)hf * 32 * 6;
    float v[6];
#pragma unroll
    for (int q = 0; q < 6; ++q) v[q] = 1e30f;
#pragma unroll
    for (int c = 0; c < 48; ++c) {
      f32x4 dv = *(const f32x4*)(cr + c * 4);
      ins6(dv[0], v);
      ins6(dv[1], v);
      ins6(dv[2], v);
      ins6(dv[3], v);
    }
    float o[6];
#pragma unroll
    for (int q = 0; q < 6; ++q) o[q] = __shfl_xor(v[q], 1, 64);
#pragma unroll
    for (int q = 0; q < 6; ++q) ins6(o[q], v);
    float term = 0.0f;
    if (hf == 0) {
      // v sorted ascending on d^2: v[0]=self (~0); mean of sqrt(v[1..5])
      const float mean = (sqrtf(v[1]) + sqrtf(v[2]) + sqrtf(v[3]) +
                          sqrtf(v[4]) + sqrtf(v[5])) * 0.2f;
      term = logf(mean + 1e-8f);
    }
#pragma unroll
    for (int off = 32; off > 0; off >>= 1) term += __shfl_down(term, off, 64);
    __syncthreads();
    if (lane == 0) red[w] = term;
    __syncthreads();
    if (t == 0) atomicAdd(accF, red[0] + red[1] + red[2] + red[3]);
  }
  if (t == 0 && nfin > 0) {
    __threadfence();
    const unsigned int c =
        atomicAdd(&ctr[0], (unsigned int)nfin) + (unsigned int)nfin;
    if (c == 64u) out[0] = -atomicAdd(accF, 0.0f) * (1.0f / 8192.0f);
  }
}

extern "C" void kernel_launch(void* const* d_in, const int* in_sizes, int n_in,
                              void* d_out, int out_size, void* d_ws, size_t ws_size,
                              hipStream_t stream) {
  const float* x = (const float*)d_in[0];
  float* out = (float*)d_out;
  char* ws = (char*)d_ws;
  unsigned char* xb = (unsigned char*)(ws + WS_XB);
  float* sq = (float*)(ws + WS_SQ);
  float* cand = (float*)(ws + WS_CAND);
  unsigned int* ctr = (unsigned int*)(ws + WS_CTR);

  cast_sq_kernel<<<B_DIM / 4, 256, 0, stream>>>(x, xb, sq, ctr);
  knn_gemm_kernel<<<NTILES, 256, 0, stream>>>(xb, sq, cand, ctr, out);
}

// Round 13
// 135.464 us; speedup vs baseline: 2.6367x; 1.5906x over previous
//
#include <hip/hip_runtime.h>
#include <hip/hip_bf16.h>
#include <hip/hip_fp8.h>

#define D_DIM 768
#define B_DIM 8192
#define NT 64           // tile grid dim (8192/128)
#define NTILES 2080     // NT*(NT+1)/2 upper-triangle tiles
#define BM 128

typedef __attribute__((ext_vector_type(4))) float f32x4;
typedef __attribute__((ext_vector_type(2))) float f32x2;
typedef __attribute__((ext_vector_type(4))) int i32x4;
typedef __attribute__((ext_vector_type(8))) int i32x8;

// ws layout (bytes)
#define WS_XB   0                               // fp8[8192*768]    = 6,291,456
#define WS_SQ   6291456                         // float[8192]      = 32,768
#define WS_CAND 6324224                         // float[8192*64*6] = 12,582,912
#define WS_ACC  18907136                        // float[1]
#define WS_TKT  18907140                        // uint[1]

__device__ __forceinline__ void gl_lds16(const void* g, void* lds) {
  __builtin_amdgcn_global_load_lds(
      (const __attribute__((address_space(1))) unsigned int*)g,
      (__attribute__((address_space(3))) unsigned int*)lds, 16, 0, 0);
}

// sort 4 values ascending (5-comparator network, 10 VALU)
__device__ __forceinline__ void sort4(float& a0, float& a1, float& a2,
                                      float& a3) {
  const float s1 = fminf(a0, a1), t1 = fmaxf(a0, a1);
  const float s2 = fminf(a2, a3), t2 = fmaxf(a2, a3);
  const float lo = fminf(s1, s2), m1 = fmaxf(s1, s2);
  const float hi = fmaxf(t1, t2), m2 = fminf(t1, t2);
  a0 = lo;
  a1 = fminf(m1, m2);
  a2 = fmaxf(m1, m2);
  a3 = hi;
}

// merge sorted a[0..3] into sorted v[0..5], keep 6 smallest (closed-form
// k-th-of-union; nested fminf chains fuse to v_min3_f32)
__device__ __forceinline__ void mrg46(float a0, float a1, float a2, float a3,
                                      float* v) {
  const float x00 = fmaxf(v[0], a0);
  const float x01 = fmaxf(v[0], a1), x10 = fmaxf(v[1], a0);
  const float x02 = fmaxf(v[0], a2), x11 = fmaxf(v[1], a1),
              x20 = fmaxf(v[2], a0);
  const float x03 = fmaxf(v[0], a3), x12 = fmaxf(v[1], a2),
              x21 = fmaxf(v[2], a1), x30 = fmaxf(v[3], a0);
  const float x13 = fmaxf(v[1], a3), x22 = fmaxf(v[2], a2),
              x31 = fmaxf(v[3], a1), x40 = fmaxf(v[4], a0);
  const float m0 = fminf(v[0], a0);
  const float m1 = fminf(fminf(v[1], a1), x00);
  const float m2 = fminf(fminf(fminf(v[2], a2), x01), x10);
  const float m3 = fminf(fminf(fminf(v[3], a3), x02), fminf(x11, x20));
  const float m4 = fminf(fminf(fminf(v[4], x03), x12), fminf(x21, x30));
  const float m5 = fminf(fminf(fminf(v[5], x13), x22), fminf(x31, x40));
  v[0] = m0; v[1] = m1; v[2] = m2; v[3] = m3; v[4] = m4; v[5] = m5;
}

// merge sorted b[0..5] into sorted v[0..5], keep 6 smallest
__device__ __forceinline__ void mrg66(const float* b, float* v) {
  const float x00 = fmaxf(v[0], b[0]);
  const float x01 = fmaxf(v[0], b[1]), x10 = fmaxf(v[1], b[0]);
  const float x02 = fmaxf(v[0], b[2]), x11 = fmaxf(v[1], b[1]),
              x20 = fmaxf(v[2], b[0]);
  const float x03 = fmaxf(v[0], b[3]), x12 = fmaxf(v[1], b[2]),
              x21 = fmaxf(v[2], b[1]), x30 = fmaxf(v[3], b[0]);
  const float x04 = fmaxf(v[0], b[4]), x13 = fmaxf(v[1], b[3]),
              x22 = fmaxf(v[2], b[2]), x31 = fmaxf(v[3], b[1]),
              x40 = fmaxf(v[4], b[0]);
  const float m0 = fminf(v[0], b[0]);
  const float m1 = fminf(fminf(v[1], b[1]), x00);
  const float m2 = fminf(fminf(fminf(v[2], b[2]), x01), x10);
  const float m3 = fminf(fminf(fminf(v[3], b[3]), x02), fminf(x11, x20));
  const float m4 =
      fminf(fminf(fminf(v[4], b[4]), x03), fminf(fminf(x12, x21), x30));
  const float m5 = fminf(fminf(fminf(v[5], b[5]), x04),
                         fminf(fminf(x13, x22), fminf(x31, x40)));
  v[0] = m0; v[1] = m1; v[2] = m2; v[3] = m3; v[4] = m4; v[5] = m5;
}

// band-blocked triangle order (16x16-tile blocks, rt-major inside). g in [0,2080).
__device__ __forceinline__ void tile_decode(int g, int& rt, int& ct) {
  int base = 0;
  for (int s = 0; s < 4; ++s) {
    for (int cb = s; cb < 4; ++cb) {
      const int sz = (cb == s) ? 136 : 256;
      if (g < base + sz) {
        int loc = g - base;
        if (cb == s) {
          int r = 0;
          while (loc >= 16 - r) {
            loc -= 16 - r;
            ++r;
          }
          rt = s * 16 + r;
          ct = cb * 16 + r + loc;
        } else {
          rt = s * 16 + (loc >> 4);
          ct = cb * 16 + (loc & 15);
        }
        return;
      }
      base += sz;
    }
  }
  rt = 0;
  ct = 0;
}

// kernel 1: cast fp32 -> fp8 e4m3 (OCP), row sum-of-squares of the DECODED fp8
// values (so self-distance rsq+rsq-2*G(i,i) stays ~0). Verified round 9/10.
__global__ __launch_bounds__(256) void cast_sq_kernel(
    const float* __restrict__ x, unsigned char* __restrict__ xb,
    float* __restrict__ sq, float* __restrict__ acc,
    unsigned int* __restrict__ tkt) {
  const int t = threadIdx.x;
  const int w = t >> 6, lane = t & 63;
  const int row = blockIdx.x * 4 + w;
  if (blockIdx.x == 0) {
    if (t == 0) acc[0] = 0.0f;
    if (t == 1) tkt[0] = 0u;
  }
  const f32x4* xr = (const f32x4*)(x + (size_t)row * D_DIM);
  unsigned int* xbr = (unsigned int*)(xb + (size_t)row * D_DIM);
  float s = 0.0f;
#pragma unroll
  for (int c = 0; c < 3; ++c) {
    const int idx = c * 64 + lane;
    f32x4 v = xr[idx];
    unsigned int p = 0;
#pragma unroll
    for (int e = 0; e < 4; ++e) {
      __hip_fp8_e4m3 h(v[e]);
      const float d = (float)h;
      s += d * d;
      p |= ((unsigned int)h.__x) << (8 * e);
    }
    xbr[idx] = p;
  }
#pragma unroll
  for (int off = 32; off > 0; off >>= 1) s += __shfl_down(s, off, 64);
  if (lane == 0) sq[row] = s;
}

// ------- kernel 2: MX-fp8 K=128 sections, symmetric 128x128 tiles, dbuf -------
// Round-10 verified core. Epilogue selection now uses sort4 + sorted-merge
// networks (8.5-10.5 VALU/value vs 11 for per-element insert; shfl merges 36
// vs 66) - the profile's largest pipe (VALUBusy 33%) is the target.
#define ABUF(b) ((b) * 32768)
#define BBUF(b) ((b) * 32768 + 16384)
#define VMW(N) asm volatile("s_waitcnt vmcnt(" #N ")" ::: "memory")
#define BAR()                         \
  {                                   \
    asm volatile("" ::: "memory");    \
    __builtin_amdgcn_s_barrier();     \
    asm volatile("" ::: "memory");    \
  }

__global__ __launch_bounds__(256, 2) void knn_gemm_kernel(
    const unsigned char* __restrict__ xb, const float* __restrict__ sq,
    float* __restrict__ cand) {
  __shared__ __align__(16) char smem[65536];
  const int t = threadIdx.x;
  const int lane = t & 63, w = t >> 6;
  const int wm = w >> 1, wn = w & 1;  // 2x2 wave grid; wave tile 64x64
  const int quad = lane >> 4, m16 = lane & 15;

  // XCD chunking (2080 = 8*260, bijective) + band-blocked decode
  const int g = (blockIdx.x & 7) * (NTILES / 8) + (blockIdx.x >> 3);
  int rt, ct;
  tile_decode(g, rt, ct);
  const bool offdiag = (ct > rt);
  const int rowBase = rt * BM, colBase = ct * BM;

  // staging: thread t covers rows (t>>3)+32q, slot t&7; inverse slot swizzle on
  // the global source. (row&3) and ((row>>2)&1) are invariant under row+=32.
  const int sR = t >> 3, sS = t & 7;
  const int q_src = ((sS >> 1) - sR) & 3;
  const int h_src = ((sS & 1) - (sR >> 2)) & 1;
  const int srcOff = q_src * 32 + h_src * 16;
  const unsigned char* pA = xb + (size_t)(rowBase + sR) * D_DIM + srcOff;
  const unsigned char* pB = xb + (size_t)(colBase + sR) * D_DIM + srcOff;

  // fragment read offsets (within a row's 128 B)
  const int pairOff = ((quad + m16) & 3) * 32;
  const int bitOff = ((m16 >> 2) & 1) * 16;
  const int laneLo = m16 * 128 + pairOff + bitOff;
  const int laneHi = m16 * 128 + pairOff + (bitOff ^ 16);
  const int aRow = wm * 8192;
  const int bRow = wn * 8192;

  float rsq[16];
#pragma unroll
  for (int i = 0; i < 4; ++i)
#pragma unroll
    for (int r = 0; r < 4; ++r)
      rsq[i * 4 + r] = sq[rowBase + wm * 64 + i * 16 + quad * 4 + r];
  float csq[4];
#pragma unroll
  for (int j = 0; j < 4; ++j) csq[j] = sq[colBase + wn * 64 + j * 16 + m16];

  f32x4 acv[4][4];
  const f32x4 zero = {0.0f, 0.0f, 0.0f, 0.0f};
#pragma unroll
  for (int i = 0; i < 4; ++i)
#pragma unroll
    for (int j = 0; j < 4; ++j) acv[i][j] = zero;

#define STAGE(P, KOFF, REGION)                                          \
  {                                                                     \
    _Pragma("unroll") for (int q = 0; q < 4; ++q)                       \
        gl_lds16((P) + (KOFF) + q * 32 * D_DIM,                         \
                 smem + (REGION) + q * 4096 + t * 16);                  \
  }

  i32x8 aF[4], bF[4];
#define LDA(BASE)                                                            \
  {                                                                          \
    _Pragma("unroll") for (int ii = 0; ii < 4; ++ii) {                       \
      i32x4 lo = *(const i32x4*)(smem + (BASE) + aRow + ii * 2048 + laneLo); \
      i32x4 hi = *(const i32x4*)(smem + (BASE) + aRow + ii * 2048 + laneHi); \
      __builtin_memcpy(&aF[ii], &lo, 16);                                    \
      __builtin_memcpy(((char*)&aF[ii]) + 16, &hi, 16);                      \
    }                                                                        \
  }
#define LDB(BASE)                                                            \
  {                                                                          \
    _Pragma("unroll") for (int j = 0; j < 4; ++j) {                          \
      i32x4 lo = *(const i32x4*)(smem + (BASE) + bRow + j * 2048 + laneLo);  \
      i32x4 hi = *(const i32x4*)(smem + (BASE) + bRow + j * 2048 + laneHi);  \
      __builtin_memcpy(&bF[j], &lo, 16);                                     \
      __builtin_memcpy(((char*)&bF[j]) + 16, &hi, 16);                       \
    }                                                                        \
  }
#define MFMAS16                                                              \
  {                                                                          \
    __builtin_amdgcn_s_setprio(1);                                           \
    _Pragma("unroll") for (int ii = 0; ii < 4; ++ii)                         \
        _Pragma("unroll") for (int j = 0; j < 4; ++j)                        \
            acv[ii][j] = __builtin_amdgcn_mfma_scale_f32_16x16x128_f8f6f4(   \
                aF[ii], bF[j], acv[ii][j], 0, 0, 0, 0x7F7F7F7F, 0,           \
                0x7F7F7F7F);                                                 \
    __builtin_amdgcn_s_setprio(0);                                           \
  }

  STAGE(pA, 0, ABUF(0));
  STAGE(pB, 0, BBUF(0));

#pragma unroll
  for (int s = 0; s < 6; ++s) {
    const int b = s & 1;
    if (s < 5) {
      STAGE(pA, (s + 1) * 128, ABUF(b ^ 1));
      STAGE(pB, (s + 1) * 128, BBUF(b ^ 1));
    }
    if (s < 5) {
      VMW(8);
    } else {
      VMW(0);
    }
    BAR();
    LDA(ABUF(b));
    LDB(BBUF(b));
    MFMAS16;
    BAR();
  }

  // ---------------- epilogue: 2 groups of 64 rows, split row/col duty ----------------
  float* distS = (float*)smem;             // [64][132] f32 = 33792 B
  float* rsqS = (float*)(smem + 33792);    // [64] f32
  float colrun[6];
#pragma unroll
  for (int q = 0; q < 6; ++q) colrun[q] = 1e30f;

#pragma unroll
  for (int gg = 0; gg < 2; ++gg) {
    BAR();
    if (wm == gg) {
      // row-key = csq[col] - 2G (row-constant rsq added at write; order-invariant)
#pragma unroll
      for (int ii = 0; ii < 4; ++ii)
#pragma unroll
        for (int j = 0; j < 4; ++j)
#pragma unroll
          for (int r = 0; r < 4; ++r)
            distS[(ii * 16 + quad * 4 + r) * 132 + wn * 64 + j * 16 + m16] =
                csq[j] - 2.0f * acv[ii][j][r];
      if (wn == 0 && m16 == 0) {
#pragma unroll
        for (int ii = 0; ii < 4; ++ii)
#pragma unroll
          for (int r = 0; r < 4; ++r)
            rsqS[ii * 16 + quad * 4 + r] = rsq[ii * 4 + r];
      }
    }
    BAR();
    if (t < 128) {
      // row-side: 2 thr/row x 64 cols, batched sort4+merge, one mrg66 partner merge
      const int row_l = t >> 1, half = t & 1;
      const float* drow = distS + row_l * 132 + half * 64;
      float v[6];
#pragma unroll
      for (int q = 0; q < 6; ++q) v[q] = 1e30f;
#pragma unroll
      for (int k = 0; k < 16; ++k) {
        f32x4 dv = *(const f32x4*)(drow + k * 4);
        float w0 = dv[0], w1 = dv[1], w2 = dv[2], w3 = dv[3];
        sort4(w0, w1, w2, w3);
        mrg46(w0, w1, w2, w3, v);
      }
      float b[6];
#pragma unroll
      for (int q = 0; q < 6; ++q) b[q] = __shfl_xor(v[q], 1, 64);
      mrg66(b, v);
      if (half == 0) {
        const int grow = rowBase + gg * 64 + row_l;
        const float rq = rsqS[row_l];
        float* o6 = cand + (size_t)(grow * NT + ct) * 6;
        f32x2 w0 = {fmaxf(v[0] + rq, 0.0f), fmaxf(v[1] + rq, 0.0f)};
        f32x2 w1 = {fmaxf(v[2] + rq, 0.0f), fmaxf(v[3] + rq, 0.0f)};
        f32x2 w2 = {fmaxf(v[4] + rq, 0.0f), fmaxf(v[5] + rq, 0.0f)};
        *(f32x2*)o6 = w0;
        *(f32x2*)(o6 + 2) = w1;
        *(f32x2*)(o6 + 4) = w2;
      }
    } else if (offdiag) {
      // col-side: 1 thr/col; key = distS + rsq[row] = full d^2, batched
      const int col = t - 128;
#pragma unroll
      for (int r4 = 0; r4 < 16; ++r4) {
        const int rr = r4 * 4;
        float w0 = distS[(rr + 0) * 132 + col] + rsqS[rr + 0];
        float w1 = distS[(rr + 1) * 132 + col] + rsqS[rr + 1];
        float w2 = distS[(rr + 2) * 132 + col] + rsqS[rr + 2];
        float w3 = distS[(rr + 3) * 132 + col] + rsqS[rr + 3];
        sort4(w0, w1, w2, w3);
        mrg46(w0, w1, w2, w3, colrun);
      }
    }
  }
  if (offdiag && t >= 128) {
    const int colg = colBase + (t - 128);
    float* o6 = cand + (size_t)(colg * NT + rt) * 6;
    f32x2 w0 = {fmaxf(colrun[0], 0.0f), fmaxf(colrun[1], 0.0f)};
    f32x2 w1 = {fmaxf(colrun[2], 0.0f), fmaxf(colrun[3], 0.0f)};
    f32x2 w2 = {fmaxf(colrun[4], 0.0f), fmaxf(colrun[5], 0.0f)};
    *(f32x2*)o6 = w0;
    *(f32x2*)(o6 + 2) = w1;
    *(f32x2*)(o6 + 4) = w2;
  }
}

// kernel 3: per-row merge of 64 chunk-candidates (each already sorted-6!)
// via mrg66 chains -> sqrt -> log -> global sum, fused finalize via ticket.
__global__ __launch_bounds__(256) void knn_merge_kernel(
    const float* __restrict__ cand, float* __restrict__ acc,
    unsigned int* __restrict__ tkt, float* __restrict__ out) {
  const int t = threadIdx.x;
  const int r = blockIdx.x * 32 + (t >> 3);
  const float* cr = cand + (size_t)r * (NT * 6) + (size_t)(t & 7) * 48;
  float v[6];
#pragma unroll
  for (int s = 0; s < 6; ++s) v[s] = 1e30f;
#pragma unroll
  for (int c = 0; c < 4; ++c) {
    f32x4 d0 = *(const f32x4*)(cr + c * 12);
    f32x4 d1 = *(const f32x4*)(cr + c * 12 + 4);
    f32x4 d2 = *(const f32x4*)(cr + c * 12 + 8);
    float b0[6] = {d0[0], d0[1], d0[2], d0[3], d1[0], d1[1]};
    mrg66(b0, v);
    float b1[6] = {d1[2], d1[3], d2[0], d2[1], d2[2], d2[3]};
    mrg66(b1, v);
  }
#pragma unroll
  for (int st = 1; st <= 4; st <<= 1) {
    float b[6];
#pragma unroll
    for (int q = 0; q < 6; ++q) b[q] = __shfl_xor(v[q], st, 64);
    mrg66(b, v);
  }
  float term = 0.0f;
  if ((t & 7) == 0) {
    // v sorted ascending on d^2: v[0] = self (~0); knn_mean = mean of sqrt(v[1..5])
    const float mean =
        (sqrtf(v[1]) + sqrtf(v[2]) + sqrtf(v[3]) + sqrtf(v[4]) + sqrtf(v[5])) * 0.2f;
    term = logf(mean + 1e-8f);
  }
#pragma unroll
  for (int off = 32; off > 0; off >>= 1) term += __shfl_down(term, off, 64);
  __shared__ float red[4];
  if ((t & 63) == 0) red[t >> 6] = term;
  __syncthreads();
  if (t == 0) {
    atomicAdd(acc, red[0] + red[1] + red[2] + red[3]);
    __threadfence();
    const unsigned int tk = atomicAdd(tkt, 1u);
    if (tk == (B_DIM / 32) - 1) {
      const float total = atomicAdd(acc, 0.0f);  // coherent read of final sum
      out[0] = -total * (1.0f / 8192.0f);
    }
  }
}

extern "C" void kernel_launch(void* const* d_in, const int* in_sizes, int n_in,
                              void* d_out, int out_size, void* d_ws, size_t ws_size,
                              hipStream_t stream) {
  const float* x = (const float*)d_in[0];
  float* out = (float*)d_out;
  char* ws = (char*)d_ws;
  unsigned char* xb = (unsigned char*)(ws + WS_XB);
  float* sq = (float*)(ws + WS_SQ);
  float* cand = (float*)(ws + WS_CAND);
  float* acc = (float*)(ws + WS_ACC);
  unsigned int* tkt = (unsigned int*)(ws + WS_TKT);

  cast_sq_kernel<<<B_DIM / 4, 256, 0, stream>>>(x, xb, sq, acc, tkt);
  knn_gemm_kernel<<<NTILES, 256, 0, stream>>>(xb, sq, cand);
  knn_merge_kernel<<<B_DIM / 32, 256, 0, stream>>>(cand, acc, tkt, out);
}

// Round 14
// 131.817 us; speedup vs baseline: 2.7097x; 1.0277x over previous
//
#include <hip/hip_runtime.h>
#include <hip/hip_bf16.h>
#include <hip/hip_fp8.h>

#define D_DIM 768
#define B_DIM 8192
#define NT 64           // tile grid dim (8192/128)
#define NTILES 2080     // NT*(NT+1)/2 upper-triangle tiles
#define BM 128

typedef __attribute__((ext_vector_type(4))) float f32x4;
typedef __attribute__((ext_vector_type(2))) float f32x2;
typedef __attribute__((ext_vector_type(4))) int i32x4;
typedef __attribute__((ext_vector_type(8))) int i32x8;

// ws layout (bytes)
#define WS_XB   0                               // fp8[8192*768]    = 6,291,456
#define WS_SQ   6291456                         // float[8192]      = 32,768
#define WS_CAND 6324224                         // float[8192*64*6] = 12,582,912
#define WS_ACC  18907136                        // float[1]
#define WS_TKT  18907140                        // uint[1]

__device__ __forceinline__ void gl_lds16(const void* g, void* lds) {
  __builtin_amdgcn_global_load_lds(
      (const __attribute__((address_space(1))) unsigned int*)g,
      (__attribute__((address_space(3))) unsigned int*)lds, 16, 0, 0);
}

// sort 4 values ascending (5-comparator network, 10 VALU)
__device__ __forceinline__ void sort4(float& a0, float& a1, float& a2,
                                      float& a3) {
  const float s1 = fminf(a0, a1), t1 = fmaxf(a0, a1);
  const float s2 = fminf(a2, a3), t2 = fmaxf(a2, a3);
  const float lo = fminf(s1, s2), m1 = fmaxf(s1, s2);
  const float hi = fmaxf(t1, t2), m2 = fminf(t1, t2);
  a0 = lo;
  a1 = fminf(m1, m2);
  a2 = fmaxf(m1, m2);
  a3 = hi;
}

// merge sorted a[0..3] into sorted v[0..5], keep 6 smallest (closed-form
// k-th-of-union; nested fminf chains fuse to v_min3_f32)
__device__ __forceinline__ void mrg46(float a0, float a1, float a2, float a3,
                                      float* v) {
  const float x00 = fmaxf(v[0], a0);
  const float x01 = fmaxf(v[0], a1), x10 = fmaxf(v[1], a0);
  const float x02 = fmaxf(v[0], a2), x11 = fmaxf(v[1], a1),
              x20 = fmaxf(v[2], a0);
  const float x03 = fmaxf(v[0], a3), x12 = fmaxf(v[1], a2),
              x21 = fmaxf(v[2], a1), x30 = fmaxf(v[3], a0);
  const float x13 = fmaxf(v[1], a3), x22 = fmaxf(v[2], a2),
              x31 = fmaxf(v[3], a1), x40 = fmaxf(v[4], a0);
  const float m0 = fminf(v[0], a0);
  const float m1 = fminf(fminf(v[1], a1), x00);
  const float m2 = fminf(fminf(fminf(v[2], a2), x01), x10);
  const float m3 = fminf(fminf(fminf(v[3], a3), x02), fminf(x11, x20));
  const float m4 = fminf(fminf(fminf(v[4], x03), x12), fminf(x21, x30));
  const float m5 = fminf(fminf(fminf(v[5], x13), x22), fminf(x31, x40));
  v[0] = m0; v[1] = m1; v[2] = m2; v[3] = m3; v[4] = m4; v[5] = m5;
}

// merge sorted b[0..5] into sorted v[0..5], keep 6 smallest
__device__ __forceinline__ void mrg66(const float* b, float* v) {
  const float x00 = fmaxf(v[0], b[0]);
  const float x01 = fmaxf(v[0], b[1]), x10 = fmaxf(v[1], b[0]);
  const float x02 = fmaxf(v[0], b[2]), x11 = fmaxf(v[1], b[1]),
              x20 = fmaxf(v[2], b[0]);
  const float x03 = fmaxf(v[0], b[3]), x12 = fmaxf(v[1], b[2]),
              x21 = fmaxf(v[2], b[1]), x30 = fmaxf(v[3], b[0]);
  const float x04 = fmaxf(v[0], b[4]), x13 = fmaxf(v[1], b[3]),
              x22 = fmaxf(v[2], b[2]), x31 = fmaxf(v[3], b[1]),
              x40 = fmaxf(v[4], b[0]);
  const float m0 = fminf(v[0], b[0]);
  const float m1 = fminf(fminf(v[1], b[1]), x00);
  const float m2 = fminf(fminf(fminf(v[2], b[2]), x01), x10);
  const float m3 = fminf(fminf(fminf(v[3], b[3]), x02), fminf(x11, x20));
  const float m4 =
      fminf(fminf(fminf(v[4], b[4]), x03), fminf(fminf(x12, x21), x30));
  const float m5 = fminf(fminf(fminf(v[5], b[5]), x04),
                         fminf(fminf(x13, x22), fminf(x31, x40)));
  v[0] = m0; v[1] = m1; v[2] = m2; v[3] = m3; v[4] = m4; v[5] = m5;
}

// band-blocked triangle order (16x16-tile blocks, rt-major inside). g in [0,2080).
__device__ __forceinline__ void tile_decode(int g, int& rt, int& ct) {
  int base = 0;
  for (int s = 0; s < 4; ++s) {
    for (int cb = s; cb < 4; ++cb) {
      const int sz = (cb == s) ? 136 : 256;
      if (g < base + sz) {
        int loc = g - base;
        if (cb == s) {
          int r = 0;
          while (loc >= 16 - r) {
            loc -= 16 - r;
            ++r;
          }
          rt = s * 16 + r;
          ct = cb * 16 + r + loc;
        } else {
          rt = s * 16 + (loc >> 4);
          ct = cb * 16 + (loc & 15);
        }
        return;
      }
      base += sz;
    }
  }
  rt = 0;
  ct = 0;
}

// kernel 1: cast fp32 -> fp8 e4m3 (OCP), row sum-of-squares of the DECODED fp8
// values (so self-distance rsq+rsq-2*G(i,i) stays ~0). Verified round 9/10.
__global__ __launch_bounds__(256) void cast_sq_kernel(
    const float* __restrict__ x, unsigned char* __restrict__ xb,
    float* __restrict__ sq, float* __restrict__ acc,
    unsigned int* __restrict__ tkt) {
  const int t = threadIdx.x;
  const int w = t >> 6, lane = t & 63;
  const int row = blockIdx.x * 4 + w;
  if (blockIdx.x == 0) {
    if (t == 0) acc[0] = 0.0f;
    if (t == 1) tkt[0] = 0u;
  }
  const f32x4* xr = (const f32x4*)(x + (size_t)row * D_DIM);
  unsigned int* xbr = (unsigned int*)(xb + (size_t)row * D_DIM);
  float s = 0.0f;
#pragma unroll
  for (int c = 0; c < 3; ++c) {
    const int idx = c * 64 + lane;
    f32x4 v = xr[idx];
    unsigned int p = 0;
#pragma unroll
    for (int e = 0; e < 4; ++e) {
      __hip_fp8_e4m3 h(v[e]);
      const float d = (float)h;
      s += d * d;
      p |= ((unsigned int)h.__x) << (8 * e);
    }
    xbr[idx] = p;
  }
#pragma unroll
  for (int off = 32; off > 0; off >>= 1) s += __shfl_down(s, off, 64);
  if (lane == 0) sq[row] = s;
}

// ------- kernel 2: MX-fp8 K=128 sections, symmetric 128x128 tiles, dbuf -------
// Round-13 verified core. Selection now uses TWO independent accumulator
// chains (even/odd batches) merged once at the end: halves the dependent
// fminf-chain latency (selection was the top pipe, VALUBusy 40%, at only
// 2 waves/SIMD of latency cover), plus init-from-first-batch.
#define ABUF(b) ((b) * 32768)
#define BBUF(b) ((b) * 32768 + 16384)
#define VMW(N) asm volatile("s_waitcnt vmcnt(" #N ")" ::: "memory")
#define BAR()                         \
  {                                   \
    asm volatile("" ::: "memory");    \
    __builtin_amdgcn_s_barrier();     \
    asm volatile("" ::: "memory");    \
  }

__global__ __launch_bounds__(256, 2) void knn_gemm_kernel(
    const unsigned char* __restrict__ xb, const float* __restrict__ sq,
    float* __restrict__ cand) {
  __shared__ __align__(16) char smem[65536];
  const int t = threadIdx.x;
  const int lane = t & 63, w = t >> 6;
  const int wm = w >> 1, wn = w & 1;  // 2x2 wave grid; wave tile 64x64
  const int quad = lane >> 4, m16 = lane & 15;

  // XCD chunking (2080 = 8*260, bijective) + band-blocked decode
  const int g = (blockIdx.x & 7) * (NTILES / 8) + (blockIdx.x >> 3);
  int rt, ct;
  tile_decode(g, rt, ct);
  const bool offdiag = (ct > rt);
  const int rowBase = rt * BM, colBase = ct * BM;

  // staging: thread t covers rows (t>>3)+32q, slot t&7; inverse slot swizzle on
  // the global source. (row&3) and ((row>>2)&1) are invariant under row+=32.
  const int sR = t >> 3, sS = t & 7;
  const int q_src = ((sS >> 1) - sR) & 3;
  const int h_src = ((sS & 1) - (sR >> 2)) & 1;
  const int srcOff = q_src * 32 + h_src * 16;
  const unsigned char* pA = xb + (size_t)(rowBase + sR) * D_DIM + srcOff;
  const unsigned char* pB = xb + (size_t)(colBase + sR) * D_DIM + srcOff;

  // fragment read offsets (within a row's 128 B)
  const int pairOff = ((quad + m16) & 3) * 32;
  const int bitOff = ((m16 >> 2) & 1) * 16;
  const int laneLo = m16 * 128 + pairOff + bitOff;
  const int laneHi = m16 * 128 + pairOff + (bitOff ^ 16);
  const int aRow = wm * 8192;
  const int bRow = wn * 8192;

  float rsq[16];
#pragma unroll
  for (int i = 0; i < 4; ++i)
#pragma unroll
    for (int r = 0; r < 4; ++r)
      rsq[i * 4 + r] = sq[rowBase + wm * 64 + i * 16 + quad * 4 + r];
  float csq[4];
#pragma unroll
  for (int j = 0; j < 4; ++j) csq[j] = sq[colBase + wn * 64 + j * 16 + m16];

  f32x4 acv[4][4];
  const f32x4 zero = {0.0f, 0.0f, 0.0f, 0.0f};
#pragma unroll
  for (int i = 0; i < 4; ++i)
#pragma unroll
    for (int j = 0; j < 4; ++j) acv[i][j] = zero;

#define STAGE(P, KOFF, REGION)                                          \
  {                                                                     \
    _Pragma("unroll") for (int q = 0; q < 4; ++q)                       \
        gl_lds16((P) + (KOFF) + q * 32 * D_DIM,                         \
                 smem + (REGION) + q * 4096 + t * 16);                  \
  }

  i32x8 aF[4], bF[4];
#define LDA(BASE)                                                            \
  {                                                                          \
    _Pragma("unroll") for (int ii = 0; ii < 4; ++ii) {                       \
      i32x4 lo = *(const i32x4*)(smem + (BASE) + aRow + ii * 2048 + laneLo); \
      i32x4 hi = *(const i32x4*)(smem + (BASE) + aRow + ii * 2048 + laneHi); \
      __builtin_memcpy(&aF[ii], &lo, 16);                                    \
      __builtin_memcpy(((char*)&aF[ii]) + 16, &hi, 16);                      \
    }                                                                        \
  }
#define LDB(BASE)                                                            \
  {                                                                          \
    _Pragma("unroll") for (int j = 0; j < 4; ++j) {                          \
      i32x4 lo = *(const i32x4*)(smem + (BASE) + bRow + j * 2048 + laneLo);  \
      i32x4 hi = *(const i32x4*)(smem + (BASE) + bRow + j * 2048 + laneHi);  \
      __builtin_memcpy(&bF[j], &lo, 16);                                     \
      __builtin_memcpy(((char*)&bF[j]) + 16, &hi, 16);                       \
    }                                                                        \
  }
#define MFMAS16                                                              \
  {                                                                          \
    __builtin_amdgcn_s_setprio(1);                                           \
    _Pragma("unroll") for (int ii = 0; ii < 4; ++ii)                         \
        _Pragma("unroll") for (int j = 0; j < 4; ++j)                        \
            acv[ii][j] = __builtin_amdgcn_mfma_scale_f32_16x16x128_f8f6f4(   \
                aF[ii], bF[j], acv[ii][j], 0, 0, 0, 0x7F7F7F7F, 0,           \
                0x7F7F7F7F);                                                 \
    __builtin_amdgcn_s_setprio(0);                                           \
  }

  STAGE(pA, 0, ABUF(0));
  STAGE(pB, 0, BBUF(0));

#pragma unroll
  for (int s = 0; s < 6; ++s) {
    const int b = s & 1;
    if (s < 5) {
      STAGE(pA, (s + 1) * 128, ABUF(b ^ 1));
      STAGE(pB, (s + 1) * 128, BBUF(b ^ 1));
    }
    if (s < 5) {
      VMW(8);
    } else {
      VMW(0);
    }
    BAR();
    LDA(ABUF(b));
    LDB(BBUF(b));
    MFMAS16;
    BAR();
  }

  // ---------------- epilogue: 2 groups of 64 rows, split row/col duty ----------------
  float* distS = (float*)smem;             // [64][132] f32 = 33792 B
  float* rsqS = (float*)(smem + 33792);    // [64] f32
  float colA[6], colB[6];
#pragma unroll
  for (int q = 0; q < 6; ++q) colA[q] = colB[q] = 1e30f;

#pragma unroll
  for (int gg = 0; gg < 2; ++gg) {
    BAR();
    if (wm == gg) {
      // row-key = csq[col] - 2G (row-constant rsq added at write; order-invariant)
#pragma unroll
      for (int ii = 0; ii < 4; ++ii)
#pragma unroll
        for (int j = 0; j < 4; ++j)
#pragma unroll
          for (int r = 0; r < 4; ++r)
            distS[(ii * 16 + quad * 4 + r) * 132 + wn * 64 + j * 16 + m16] =
                csq[j] - 2.0f * acv[ii][j][r];
      if (wn == 0 && m16 == 0) {
#pragma unroll
        for (int ii = 0; ii < 4; ++ii)
#pragma unroll
          for (int r = 0; r < 4; ++r)
            rsqS[ii * 16 + quad * 4 + r] = rsq[ii * 4 + r];
      }
    }
    BAR();
    if (t < 128) {
      // row-side: 2 thr/row x 64 cols; dual independent chains (even/odd batch)
      const int row_l = t >> 1, half = t & 1;
      const float* drow = distS + row_l * 132 + half * 64;
      float vA[6], vB[6];
      {
        f32x4 dv = *(const f32x4*)(drow);
        float w0 = dv[0], w1 = dv[1], w2 = dv[2], w3 = dv[3];
        sort4(w0, w1, w2, w3);
        vA[0] = w0; vA[1] = w1; vA[2] = w2; vA[3] = w3;
        vA[4] = 1e30f; vA[5] = 1e30f;
      }
      {
        f32x4 dv = *(const f32x4*)(drow + 4);
        float w0 = dv[0], w1 = dv[1], w2 = dv[2], w3 = dv[3];
        sort4(w0, w1, w2, w3);
        vB[0] = w0; vB[1] = w1; vB[2] = w2; vB[3] = w3;
        vB[4] = 1e30f; vB[5] = 1e30f;
      }
#pragma unroll
      for (int k = 2; k < 16; k += 2) {
        {
          f32x4 dv = *(const f32x4*)(drow + k * 4);
          float w0 = dv[0], w1 = dv[1], w2 = dv[2], w3 = dv[3];
          sort4(w0, w1, w2, w3);
          mrg46(w0, w1, w2, w3, vA);
        }
        {
          f32x4 dv = *(const f32x4*)(drow + k * 4 + 4);
          float w0 = dv[0], w1 = dv[1], w2 = dv[2], w3 = dv[3];
          sort4(w0, w1, w2, w3);
          mrg46(w0, w1, w2, w3, vB);
        }
      }
      mrg66(vB, vA);
      float b[6];
#pragma unroll
      for (int q = 0; q < 6; ++q) b[q] = __shfl_xor(vA[q], 1, 64);
      mrg66(b, vA);
      if (half == 0) {
        const int grow = rowBase + gg * 64 + row_l;
        const float rq = rsqS[row_l];
        float* o6 = cand + (size_t)(grow * NT + ct) * 6;
        f32x2 w0 = {fmaxf(vA[0] + rq, 0.0f), fmaxf(vA[1] + rq, 0.0f)};
        f32x2 w1 = {fmaxf(vA[2] + rq, 0.0f), fmaxf(vA[3] + rq, 0.0f)};
        f32x2 w2 = {fmaxf(vA[4] + rq, 0.0f), fmaxf(vA[5] + rq, 0.0f)};
        *(f32x2*)o6 = w0;
        *(f32x2*)(o6 + 2) = w1;
        *(f32x2*)(o6 + 4) = w2;
      }
    } else if (offdiag) {
      // col-side: 1 thr/col; key = distS + rsq[row] = full d^2; dual chains
      const int col = t - 128;
#pragma unroll
      for (int r4 = 0; r4 < 16; r4 += 2) {
        {
          const int rr = r4 * 4;
          float w0 = distS[(rr + 0) * 132 + col] + rsqS[rr + 0];
          float w1 = distS[(rr + 1) * 132 + col] + rsqS[rr + 1];
          float w2 = distS[(rr + 2) * 132 + col] + rsqS[rr + 2];
          float w3 = distS[(rr + 3) * 132 + col] + rsqS[rr + 3];
          sort4(w0, w1, w2, w3);
          mrg46(w0, w1, w2, w3, colA);
        }
        {
          const int rr = (r4 + 1) * 4;
          float w0 = distS[(rr + 0) * 132 + col] + rsqS[rr + 0];
          float w1 = distS[(rr + 1) * 132 + col] + rsqS[rr + 1];
          float w2 = distS[(rr + 2) * 132 + col] + rsqS[rr + 2];
          float w3 = distS[(rr + 3) * 132 + col] + rsqS[rr + 3];
          sort4(w0, w1, w2, w3);
          mrg46(w0, w1, w2, w3, colB);
        }
      }
    }
  }
  if (offdiag && t >= 128) {
    mrg66(colB, colA);
    const int colg = colBase + (t - 128);
    float* o6 = cand + (size_t)(colg * NT + rt) * 6;
    f32x2 w0 = {fmaxf(colA[0], 0.0f), fmaxf(colA[1], 0.0f)};
    f32x2 w1 = {fmaxf(colA[2], 0.0f), fmaxf(colA[3], 0.0f)};
    f32x2 w2 = {fmaxf(colA[4], 0.0f), fmaxf(colA[5], 0.0f)};
    *(f32x2*)o6 = w0;
    *(f32x2*)(o6 + 2) = w1;
    *(f32x2*)(o6 + 4) = w2;
  }
}

// kernel 3: per-row merge of 64 chunk-candidates (each already sorted-6)
// via two independent mrg66 chains -> sqrt -> log -> global sum, fused
// finalize via ticket (last block writes the output).
__global__ __launch_bounds__(256) void knn_merge_kernel(
    const float* __restrict__ cand, float* __restrict__ acc,
    unsigned int* __restrict__ tkt, float* __restrict__ out) {
  const int t = threadIdx.x;
  const int r = blockIdx.x * 32 + (t >> 3);
  const float* cr = cand + (size_t)r * (NT * 6) + (size_t)(t & 7) * 48;
  float vA[6], vB[6];
  {
    f32x4 d0 = *(const f32x4*)(cr);
    f32x4 d1 = *(const f32x4*)(cr + 4);
    f32x4 d2 = *(const f32x4*)(cr + 8);
    vA[0] = d0[0]; vA[1] = d0[1]; vA[2] = d0[2]; vA[3] = d0[3];
    vA[4] = d1[0]; vA[5] = d1[1];
    vB[0] = d1[2]; vB[1] = d1[3]; vB[2] = d2[0]; vB[3] = d2[1];
    vB[4] = d2[2]; vB[5] = d2[3];
  }
#pragma unroll
  for (int c = 1; c < 4; ++c) {
    f32x4 d0 = *(const f32x4*)(cr + c * 12);
    f32x4 d1 = *(const f32x4*)(cr + c * 12 + 4);
    f32x4 d2 = *(const f32x4*)(cr + c * 12 + 8);
    float b0[6] = {d0[0], d0[1], d0[2], d0[3], d1[0], d1[1]};
    mrg66(b0, vA);
    float b1[6] = {d1[2], d1[3], d2[0], d2[1], d2[2], d2[3]};
    mrg66(b1, vB);
  }
  mrg66(vB, vA);
#pragma unroll
  for (int st = 1; st <= 4; st <<= 1) {
    float b[6];
#pragma unroll
    for (int q = 0; q < 6; ++q) b[q] = __shfl_xor(vA[q], st, 64);
    mrg66(b, vA);
  }
  float term = 0.0f;
  if ((t & 7) == 0) {
    // vA sorted ascending on d^2: vA[0]=self (~0); knn_mean = mean sqrt(vA[1..5])
    const float mean = (sqrtf(vA[1]) + sqrtf(vA[2]) + sqrtf(vA[3]) +
                        sqrtf(vA[4]) + sqrtf(vA[5])) * 0.2f;
    term = logf(mean + 1e-8f);
  }
#pragma unroll
  for (int off = 32; off > 0; off >>= 1) term += __shfl_down(term, off, 64);
  __shared__ float red[4];
  if ((t & 63) == 0) red[t >> 6] = term;
  __syncthreads();
  if (t == 0) {
    atomicAdd(acc, red[0] + red[1] + red[2] + red[3]);
    __threadfence();
    const unsigned int tk = atomicAdd(tkt, 1u);
    if (tk == (B_DIM / 32) - 1) {
      const float total = atomicAdd(acc, 0.0f);  // coherent read of final sum
      out[0] = -total * (1.0f / 8192.0f);
    }
  }
}

extern "C" void kernel_launch(void* const* d_in, const int* in_sizes, int n_in,
                              void* d_out, int out_size, void* d_ws, size_t ws_size,
                              hipStream_t stream) {
  const float* x = (const float*)d_in[0];
  float* out = (float*)d_out;
  char* ws = (char*)d_ws;
  unsigned char* xb = (unsigned char*)(ws + WS_XB);
  float* sq = (float*)(ws + WS_SQ);
  float* cand = (float*)(ws + WS_CAND);
  float* acc = (float*)(ws + WS_ACC);
  unsigned int* tkt = (unsigned int*)(ws + WS_TKT);

  cast_sq_kernel<<<B_DIM / 4, 256, 0, stream>>>(x, xb, sq, acc, tkt);
  knn_gemm_kernel<<<NTILES, 256, 0, stream>>>(xb, sq, cand);
  knn_merge_kernel<<<B_DIM / 32, 256, 0, stream>>>(cand, acc, tkt, out);
}